// Round 6
// baseline (453.099 us; speedup 1.0000x reference)
//
#include <hip/hip_runtime.h>
#include <hip/hip_bf16.h>
#include <math.h>

namespace {

typedef unsigned short u16;
typedef unsigned int u32;

constexpr int LSEQ = 22, CD = 128, DI = 256, TDIM = 64;

// LDS strides (u16). Row stride mod 32 words == 2 -> 2-way bank alias (free).
constexpr int XS_LD = 132;
constexpr int XI_LD = 260;
constexpr int YLD   = 264;   // K2' y stride (matches old K2 fold layout)
constexpr int Y2_LD = 132;   // f32

// ---- K1a pool: xs[0,2904) xi[2904,8624) ----  17.2 KB
constexpr int A_XS = 0;
constexpr int A_XI = 2904;
constexpr int A_N  = 8624;

// ---- mono fallback pool (R2 config + stride fix): scr/xs[0,2904) xi z ----
constexpr int M_XI = 2904;
constexpr int M_Z  = 8624;
constexpr int M_N  = 14344;   // 28.7 KB -> 5 blocks/CU

// ---- K2' pool: yf[0,5808) yb[5808,11616) dtbc f32[1760] [11616,15136) ----
constexpr int S_YF   = 0;
constexpr int S_YB   = 5808;
constexpr int S_DTBC = 11616;
constexpr int S_N    = 15136;  // 30.3 KB; 512 thr -> 4 blocks/CU (wave cap)

// ws segments (u16 element offsets)
constexpr int WS_F_IN_HI = 0;        // 512x128
constexpr int WS_F_IN_LO = 65536;
constexpr int WS_B_IN_HI = 131072;
constexpr int WS_B_IN_LO = 196608;
constexpr int WS_F_OUT   = 262144;   // 128x256 (prep_fold)
constexpr int WS_B_OUT   = 294912;
constexpr int WS_F_XP_HI = 360448;   // 48x256 (rows 40..47 zero)
constexpr int WS_F_XP_LO = 372736;
constexpr int WS_B_XP_HI = 385024;
constexpr int WS_B_XP_LO = 397312;
constexpr int WS_TOTAL   = 409600;
// Av2 = -exp(Alog)*log2e, f32[2][256][16] at float-offset 204800
constexpr int F_AV2      = 204800;          // u16 [409600, 425984)
// mono-only: y staging
constexpr int WS_MONO_Y  = 425984;          // 2048*11264 u16 -> 47 MB total
// split-only (overlaps mono y; paths exclusive):
constexpr int F_DT       = 212992;          // f32 [4096][176]
constexpr int F_BC       = 933888;          // f32 [4096][704]
constexpr int WS_XC      = 7634944;         // bf16 [4096][5632]
constexpr int WS_G       = 30703616;        // bf16 [4096][5632]
constexpr long long WS_END_U16 = 53772288LL;
constexpr size_t NEED_SPLIT = (size_t)WS_END_U16 * 2;   // 107.5 MB
constexpr size_t NEED_MONO  = (size_t)(WS_MONO_Y + 2048LL * 11264) * 2;

typedef __attribute__((ext_vector_type(8))) short bf16x8;
typedef __attribute__((ext_vector_type(4))) short bf16x4;
typedef __attribute__((ext_vector_type(4))) float f32x4;

__device__ __forceinline__ u16 f2bf(float f) {
  __bf16 b = (__bf16)f;
  return *reinterpret_cast<u16*>(&b);
}
__device__ __forceinline__ float bf2f(u16 h) {
  return __uint_as_float(((u32)h) << 16);
}
__device__ __forceinline__ float sigm(float x) {
  float e = __builtin_amdgcn_exp2f(-1.44269504f * x);
  return __builtin_amdgcn_rcpf(1.0f + e);
}

__global__ void prep_weights(const float* __restrict__ f_in, const float* __restrict__ b_in,
                             const float* __restrict__ f_xp, const float* __restrict__ b_xp,
                             u16* __restrict__ ws) {
  int i = blockIdx.x * 256 + threadIdx.x;
  if (i >= WS_TOTAL) return;
  u16 r = 0;
  if (i < WS_F_IN_LO) {
    r = f2bf(f_in[i]);
  } else if (i < WS_B_IN_HI) {
    float v = f_in[i - WS_F_IN_LO];
    r = f2bf(v - bf2f(f2bf(v)));
  } else if (i < WS_B_IN_LO) {
    r = f2bf(b_in[i - WS_B_IN_HI]);
  } else if (i < WS_F_OUT) {
    float v = b_in[i - WS_B_IN_LO];
    r = f2bf(v - bf2f(f2bf(v)));
  } else if (i < WS_F_XP_HI) {
    r = 0;
  } else if (i < WS_F_XP_LO) {
    int j = i - WS_F_XP_HI, n = j >> 8, k = j & 255;
    r = (n < 40) ? f2bf(f_xp[n * 256 + k]) : (u16)0;
  } else if (i < WS_B_XP_HI) {
    int j = i - WS_F_XP_LO, n = j >> 8, k = j & 255;
    if (n < 40) { float v = f_xp[n * 256 + k]; r = f2bf(v - bf2f(f2bf(v))); } else r = 0;
  } else if (i < WS_B_XP_LO) {
    int j = i - WS_B_XP_HI, n = j >> 8, k = j & 255;
    r = (n < 40) ? f2bf(b_xp[n * 256 + k]) : (u16)0;
  } else {
    int j = i - WS_B_XP_LO, n = j >> 8, k = j & 255;
    if (n < 40) { float v = b_xp[n * 256 + k]; r = f2bf(v - bf2f(f2bf(v))); } else r = 0;
  }
  ws[i] = r;
}

__global__ void prep_av2(const float* __restrict__ fA, const float* __restrict__ bA,
                         u16* __restrict__ ws) {
  int i = blockIdx.x * 256 + threadIdx.x;   // 8192 = 2 x 256 x 16
  if (i >= 8192) return;
  const float* A = (i < 4096) ? fA : bA;
  ((float*)ws)[F_AV2 + i] = -__expf(A[i & 4095]) * 1.44269504f;
}

__global__ void prep_fold(const float* __restrict__ f_out, const float* __restrict__ b_out,
                          const float* __restrict__ fuse, u16* __restrict__ ws) {
  int i = blockIdx.x * 256 + threadIdx.x;
  int half = i >> 15;
  int j = i & 32767;
  int c = j >> 8, d = j & 255;
  const float* ow = half ? b_out : f_out;
  const float* fw = fuse + c * 256 + half * 128;
  float acc = 0.f;
#pragma unroll 4
  for (int k = 0; k < 128; ++k) acc = fmaf(fw[k], ow[k * 256 + d], acc);
  ws[(half ? WS_B_OUT : WS_F_OUT) + c * 256 + d] = f2bf(acc);
}

// ============ K1a: per (b, dir) — in_proj MFMA, conv, x_proj MFMA ============
// Outputs to ws: g (bf16, from P1 regs), xc (bf16), dt/bc (f32).
__global__ __launch_bounds__(256, 6) void mamba_gemm_kernel(
    const float* __restrict__ x,
    const float* __restrict__ f_conv_w, const float* __restrict__ f_conv_b,
    const float* __restrict__ b_conv_w, const float* __restrict__ b_conv_b,
    u16* __restrict__ ws)
{
  __shared__ __align__(16) u16 pool[A_N];
  u16* xs  = pool + A_XS;
  u16* xiD = pool + A_XI;

  const int tid = threadIdx.x;
  const int wv = tid >> 6, ln = tid & 63, lr = ln & 15, lg = ln >> 4;
  const int bid = blockIdx.x;
  const int b = bid >> 1, dir = bid & 1;
  const int bd = b * 2 + dir;
  const int nm = b / TDIM, t = b - nm * TDIM;
  const size_t base = (size_t)nm * CD * (TDIM * LSEQ) + (size_t)t * LSEQ;

  const int ra0 = (lr < LSEQ) ? lr : (LSEQ - 1);
  const int ra1 = (16 + lr < LSEQ) ? (16 + lr) : (LSEQ - 1);

  // stage xs
#pragma unroll
  for (int k = 0; k < 11; ++k) {
    int idx = tid + k * 256;
    int c = idx / LSEQ, v = idx - c * LSEQ;
    xs[v * XS_LD + c] = f2bf(x[base + (size_t)c * (TDIM * LSEQ) + v]);
  }
  __syncthreads();

  // P1: in_proj. waves 0,1 -> xi (LDS); waves 2,3 -> g = silu(z) -> ws (regs only)
  {
    bf16x8 afr[2][4];
#pragma unroll
    for (int kt = 0; kt < 4; ++kt) {
      afr[0][kt] = *(const bf16x8*)&xs[ra0 * XS_LD + kt * 32 + lg * 8];
      afr[1][kt] = *(const bf16x8*)&xs[ra1 * XS_LD + kt * 32 + lg * 8];
    }
    const u16* ih = ws + (dir ? WS_B_IN_HI : WS_F_IN_HI);
    const u16* il = ws + (dir ? WS_B_IN_LO : WS_F_IN_LO);
    u16* wsG = ws + WS_G + (size_t)bd * 5632;
    const bool isz = (wv >= 2);
    const int cb0 = (wv & 1) * 128;
#pragma unroll
    for (int half = 0; half < 2; ++half) {
      f32x4 acc[2][4];
#pragma unroll
      for (int m = 0; m < 2; ++m)
#pragma unroll
        for (int n = 0; n < 4; ++n) acc[m][n] = f32x4{0.f, 0.f, 0.f, 0.f};
#pragma unroll
      for (int kt = 0; kt < 4; ++kt) {
        bf16x8 bh[4], bl[4];
#pragma unroll
        for (int n = 0; n < 4; ++n) {
          const int off = (wv * 128 + (half * 4 + n) * 16 + lr) * 128 + kt * 32 + lg * 8;
          bh[n] = *(const bf16x8*)(ih + off);
          bl[n] = *(const bf16x8*)(il + off);
        }
#pragma unroll
        for (int n = 0; n < 4; ++n) {
          acc[0][n] = __builtin_amdgcn_mfma_f32_16x16x32_bf16(afr[0][kt], bh[n], acc[0][n], 0, 0, 0);
          acc[0][n] = __builtin_amdgcn_mfma_f32_16x16x32_bf16(afr[0][kt], bl[n], acc[0][n], 0, 0, 0);
          acc[1][n] = __builtin_amdgcn_mfma_f32_16x16x32_bf16(afr[1][kt], bh[n], acc[1][n], 0, 0, 0);
          acc[1][n] = __builtin_amdgcn_mfma_f32_16x16x32_bf16(afr[1][kt], bl[n], acc[1][n], 0, 0, 0);
        }
      }
#pragma unroll
      for (int m = 0; m < 2; ++m)
#pragma unroll
        for (int n = 0; n < 4; ++n)
#pragma unroll
          for (int j = 0; j < 4; ++j) {
            int row = 16 * m + lg * 4 + j;
            if (row < LSEQ) {
              int rr = dir ? (LSEQ - 1 - row) : row;    // bwd: stored reversed
              int col = cb0 + half * 64 + n * 16 + lr;
              float v = acc[m][n][j];
              if (isz) wsG[rr * DI + col] = f2bf(v * sigm(v));
              else     xiD[rr * XI_LD + col] = f2bf(v);
            }
          }
    }
  }
  __syncthreads();

  // P2: causal depthwise conv + SiLU, in-place
  {
    const int d = tid;
    const float* cw  = dir ? b_conv_w : f_conv_w;
    const float* cbp = dir ? b_conv_b : f_conv_b;
    float4 w4 = *(const float4*)(cw + d * 4);
    float bb = cbp[d];
    float w0 = 0.f, w1 = 0.f, w2 = 0.f;
    float nxt = bf2f(xiD[d]);
#pragma unroll
    for (int l = 0; l < LSEQ; ++l) {
      float w3 = nxt;
      if (l + 1 < LSEQ) nxt = bf2f(xiD[(l + 1) * XI_LD + d]);
      float a = fmaf(w0, w4.x, bb);
      a = fmaf(w1, w4.y, a);
      a = fmaf(w2, w4.z, a);
      a = fmaf(w3, w4.w, a);
      float s = a * sigm(a);
      xiD[l * XI_LD + d] = f2bf(s);
      w0 = w1; w1 = w2; w2 = w3;
    }
  }
  __syncthreads();

  // P3: x_proj MFMA -> dt/bc f32 to ws (regs only)
  float* dtO = (float*)ws + F_DT + (size_t)bd * 176;
  float* bcO = (float*)ws + F_BC + (size_t)bd * 704;
  for (int tt = wv; tt < 6; tt += 4) {
    const int mt = tt / 3, nt = tt - mt * 3;
    const u16* xph = ws + (dir ? WS_B_XP_HI : WS_F_XP_HI);
    const u16* xpl = ws + (dir ? WS_B_XP_LO : WS_F_XP_LO);
    const int raa = (mt * 16 + lr < LSEQ) ? (mt * 16 + lr) : (LSEQ - 1);
    f32x4 acc = f32x4{0.f, 0.f, 0.f, 0.f};
    const u16* bh_p = xph + (nt * 16 + lr) * 256 + lg * 8;
    const u16* bl_p = xpl + (nt * 16 + lr) * 256 + lg * 8;
#pragma unroll
    for (int kt = 0; kt < 8; kt += 2) {
      bf16x8 a0  = *(const bf16x8*)&xiD[raa * XI_LD + kt * 32 + lg * 8];
      bf16x8 a1  = *(const bf16x8*)&xiD[raa * XI_LD + (kt + 1) * 32 + lg * 8];
      bf16x8 bh0 = *(const bf16x8*)(bh_p + kt * 32);
      bf16x8 bl0 = *(const bf16x8*)(bl_p + kt * 32);
      bf16x8 bh1 = *(const bf16x8*)(bh_p + (kt + 1) * 32);
      bf16x8 bl1 = *(const bf16x8*)(bl_p + (kt + 1) * 32);
      acc = __builtin_amdgcn_mfma_f32_16x16x32_bf16(a0, bh0, acc, 0, 0, 0);
      acc = __builtin_amdgcn_mfma_f32_16x16x32_bf16(a0, bl0, acc, 0, 0, 0);
      acc = __builtin_amdgcn_mfma_f32_16x16x32_bf16(a1, bh1, acc, 0, 0, 0);
      acc = __builtin_amdgcn_mfma_f32_16x16x32_bf16(a1, bl1, acc, 0, 0, 0);
    }
    const int col = nt * 16 + lr;
#pragma unroll
    for (int j = 0; j < 4; ++j) {
      int row = mt * 16 + lg * 4 + j;
      if (row < LSEQ) {
        if (col < 8) dtO[row * 8 + col] = acc[j];
        else if (col < 40) bcO[row * 32 + (col - 8)] = acc[j];
      }
    }
  }
  // xc copy-out (xc final since P2 barrier; no extra sync needed)
  {
    u16* xcO = ws + WS_XC + (size_t)bd * 5632;
    for (int idx = tid; idx < LSEQ * 64; idx += 256) {   // 1408 x bf16x4
      int l = idx >> 6, ch = (idx & 63) * 4;
      *(bf16x4*)&xcO[l * DI + ch] = *(const bf16x4*)&xiD[l * XI_LD + ch];
    }
  }
}

// ============ K2': per b — scan(both dirs) + fold MFMA + LayerNorm ============
// 512 threads: tid<256 -> fwd channel, tid>=256 -> bwd channel. y stays in LDS.
__global__ __launch_bounds__(512, 8) void scan_fold_ln_kernel(
    const float* __restrict__ f_dt_w, const float* __restrict__ f_dt_b,
    const float* __restrict__ f_D,
    const float* __restrict__ b_dt_w, const float* __restrict__ b_dt_b,
    const float* __restrict__ b_D,
    const float* __restrict__ ln_w, const float* __restrict__ ln_b,
    const u16* __restrict__ ws, float* __restrict__ out)
{
  __shared__ __align__(16) u16 pool[S_N];
  float* scanf32 = (float*)(pool + S_DTBC);   // [dt0 176][dt1 176][bc0 704][bc1 704]

  const int tid = threadIdx.x;
  const int b = blockIdx.x;
  const int nm = b / TDIM, t = b - nm * TDIM;
  const size_t base = (size_t)nm * CD * (TDIM * LSEQ) + (size_t)t * LSEQ;

  // ---- stage dt/bc (f32) into LDS ----
  {
    const float* wsf = (const float*)ws;
    for (int idx = tid; idx < 1760; idx += 512) {
      float v;
      if (idx < 352) {          // dt: dir = idx/176
        int dirc = idx / 176, r = idx - dirc * 176;
        v = wsf[F_DT + (size_t)(b * 2 + dirc) * 176 + r];
      } else {                  // bc
        int j = idx - 352;
        int dirc = j / 704, r = j - dirc * 704;
        v = wsf[F_BC + (size_t)(b * 2 + dirc) * 704 + r];
      }
      scanf32[idx] = v;
    }
  }
  __syncthreads();

  // ---- scan (each thread: one (dir, channel)) ----
  {
    const int dir = tid >> 8, d = tid & 255;
    const int bd = b * 2 + dir;
    const float* dtw  = dir ? b_dt_w : f_dt_w;
    const float* dtb  = dir ? b_dt_b : f_dt_b;
    const float* Dp   = dir ? b_D : f_D;
    const float* av2p = (const float*)ws + F_AV2 + dir * 4096 + d * 16;
    const u16* xcp = ws + WS_XC + (size_t)bd * 5632;
    const u16* gp  = ws + WS_G  + (size_t)bd * 5632;
    const float* dtL = scanf32 + dir * 176;
    const float* bcL = scanf32 + 352 + dir * 704;
    u16* yL = pool + (dir ? S_YB : S_YF);

    float4 dw0 = *(const float4*)(dtw + d * 8);
    float4 dw1 = *(const float4*)(dtw + d * 8 + 4);
    const float dtbv = dtb[d];
    float Av2[16];
#pragma unroll
    for (int s4 = 0; s4 < 4; ++s4) {
      float4 a = *(const float4*)(av2p + s4 * 4);
      Av2[s4 * 4 + 0] = a.x; Av2[s4 * 4 + 1] = a.y;
      Av2[s4 * 4 + 2] = a.z; Av2[s4 * 4 + 3] = a.w;
    }
    const float Dd = Dp[d];

    auto softp8 = [&](float4 q0, float4 q1) -> float {
      float sdt = dtbv;
      sdt = fmaf(q0.x, dw0.x, sdt); sdt = fmaf(q0.y, dw0.y, sdt);
      sdt = fmaf(q0.z, dw0.z, sdt); sdt = fmaf(q0.w, dw0.w, sdt);
      sdt = fmaf(q1.x, dw1.x, sdt); sdt = fmaf(q1.y, dw1.y, sdt);
      sdt = fmaf(q1.z, dw1.z, sdt); sdt = fmaf(q1.w, dw1.w, sdt);
      return (sdt > 20.f) ? sdt : __logf(1.f + __expf(sdt));
    };

    float h[16];
#pragma unroll
    for (int s = 0; s < 16; ++s) h[s] = 0.f;

#define SC(s, bv, cv) { float dA = __builtin_amdgcn_exp2f(dtv * Av2[s]); \
      h[s] = fmaf(dA, h[s], du * (bv)); \
      acc = fmaf(h[s], (cv), acc); }
    auto STEP = [&](int l, float dtv) {
      float u = bf2f(xcp[l * DI + d]);
      float g = bf2f(gp[l * DI + d]);
      float4 b0 = *(const float4*)(bcL + l * 32);
      float4 b1 = *(const float4*)(bcL + l * 32 + 4);
      float4 b2 = *(const float4*)(bcL + l * 32 + 8);
      float4 b3 = *(const float4*)(bcL + l * 32 + 12);
      float4 c0 = *(const float4*)(bcL + l * 32 + 16);
      float4 c1 = *(const float4*)(bcL + l * 32 + 20);
      float4 c2 = *(const float4*)(bcL + l * 32 + 24);
      float4 c3 = *(const float4*)(bcL + l * 32 + 28);
      float du = dtv * u;
      float acc = 0.f;
      SC(0, b0.x, c0.x) SC(1, b0.y, c0.y) SC(2, b0.z, c0.z) SC(3, b0.w, c0.w)
      SC(4, b1.x, c1.x) SC(5, b1.y, c1.y) SC(6, b1.z, c1.z) SC(7, b1.w, c1.w)
      SC(8, b2.x, c2.x) SC(9, b2.y, c2.y) SC(10, b2.z, c2.z) SC(11, b2.w, c2.w)
      SC(12, b3.x, c3.x) SC(13, b3.y, c3.y) SC(14, b3.z, c3.z) SC(15, b3.w, c3.w)
      float yo = fmaf(u, Dd, acc) * g;
      yL[(dir ? (LSEQ - 1 - l) : l) * YLD + d] = f2bf(yo);
    };
#undef SC

    float4 qa0 = *(const float4*)(dtL + 0);
    float4 qa1 = *(const float4*)(dtL + 4);
    float4 qb0 = *(const float4*)(dtL + 8);
    float4 qb1 = *(const float4*)(dtL + 12);
    float dtvA = softp8(qa0, qa1);
    float dtvB = softp8(qb0, qb1);
    for (int ll = 0; ll < LSEQ; ll += 2) {
      const int l2 = (ll + 2 < LSEQ) ? (ll + 2) : (LSEQ - 2);
      qa0 = *(const float4*)(dtL + l2 * 8);
      qa1 = *(const float4*)(dtL + l2 * 8 + 4);
      qb0 = *(const float4*)(dtL + l2 * 8 + 8);
      qb1 = *(const float4*)(dtL + l2 * 8 + 12);
      STEP(ll, dtvA);
      STEP(ll + 1, dtvB);
      dtvA = softp8(qa0, qa1);
      dtvB = softp8(qb0, qb1);
    }
  }
  __syncthreads();

  // ---- fold MFMA: y2 = y_f @ Wf.T + y_b @ Wb.T (8 waves x 16 cols) ----
  const int wv = tid >> 6, ln = tid & 63, lr = ln & 15, lg = ln >> 4;
  const int ra0 = (lr < LSEQ) ? lr : (LSEQ - 1);
  const int ra1 = (16 + lr < LSEQ) ? (16 + lr) : (LSEQ - 1);
  f32x4 acc[2] = {f32x4{0.f, 0.f, 0.f, 0.f}, f32x4{0.f, 0.f, 0.f, 0.f}};
#pragma unroll
  for (int dirc = 0; dirc < 2; ++dirc) {
    const u16* wp = ws + (dirc ? WS_B_OUT : WS_F_OUT);
    const u16* yD = pool + (dirc ? S_YB : S_YF);
#pragma unroll
    for (int kt = 0; kt < 8; ++kt) {
      bf16x8 a0 = *(const bf16x8*)&yD[ra0 * YLD + kt * 32 + lg * 8];
      bf16x8 a1 = *(const bf16x8*)&yD[ra1 * YLD + kt * 32 + lg * 8];
      bf16x8 bw = *(const bf16x8*)(wp + (wv * 16 + lr) * 256 + kt * 32 + lg * 8);
      acc[0] = __builtin_amdgcn_mfma_f32_16x16x32_bf16(a0, bw, acc[0], 0, 0, 0);
      acc[1] = __builtin_amdgcn_mfma_f32_16x16x32_bf16(a1, bw, acc[1], 0, 0, 0);
    }
  }
  __syncthreads();   // all reads of yD done before y2 overlay

  float* y2 = (float*)pool;   // [22][132] f32, overlays yf
#pragma unroll
  for (int m = 0; m < 2; ++m)
#pragma unroll
    for (int j = 0; j < 4; ++j) {
      int row = 16 * m + lg * 4 + j;
      if (row < LSEQ) y2[row * Y2_LD + wv * 16 + lr] = acc[m][j];
    }
  __syncthreads();

  // ---- LayerNorm stats (one wave per row) ----
  float* mu_s = (float*)(pool + S_YB);   // overlays yb
  float* rs_s = mu_s + LSEQ;
  for (int l = wv; l < LSEQ; l += 8) {
    float v1 = y2[l * Y2_LD + ln];
    float v2 = y2[l * Y2_LD + 64 + ln];
    float s = v1 + v2;
    float sq = v1 * v1 + v2 * v2;
#pragma unroll
    for (int m = 1; m < 64; m <<= 1) {
      s  += __shfl_xor(s, m, 64);
      sq += __shfl_xor(sq, m, 64);
    }
    if (ln == 0) {
      float mu = s * (1.0f / 128.0f);
      float var = sq * (1.0f / 128.0f) - mu * mu;
      mu_s[l] = mu;
      rs_s[l] = rsqrtf(var + 1e-5f);
    }
  }
  __syncthreads();

  // ---- normalize + transposed store ----
  for (int idx = tid; idx < LSEQ * CD; idx += 512) {
    int c = idx / LSEQ, v = idx - c * LSEQ;
    float yv = y2[v * Y2_LD + c];
    float o = (yv - mu_s[v]) * rs_s[v] * ln_w[c] + ln_b[c];
    out[base + (size_t)c * (TDIM * LSEQ) + v] = o;
  }
}

// ============ Fallback: R2-config monolithic (5 blk/CU) + old fold_ln ============
__global__ __launch_bounds__(256, 5) void mamba_scan_mono(
    const float* __restrict__ x,
    const float* __restrict__ f_conv_w, const float* __restrict__ f_conv_b,
    const float* __restrict__ f_dt_w, const float* __restrict__ f_dt_b,
    const float* __restrict__ f_Alog, const float* __restrict__ f_D,
    const float* __restrict__ b_conv_w, const float* __restrict__ b_conv_b,
    const float* __restrict__ b_dt_w, const float* __restrict__ b_dt_b,
    const float* __restrict__ b_Alog, const float* __restrict__ b_D,
    u16* __restrict__ ws)
{
  __shared__ __align__(16) u16 pool[M_N];
  u16* xs  = pool;                       // [0,2904) overlays dtbc (written P3)
  u16* xiD = pool + M_XI;
  u16* zD  = pool + M_Z;
  float* dtD = (float*)pool;             // f32[22][8]
  float* bcD = dtD + 176;                // f32[22][32]

  const int tid = threadIdx.x;
  const int wv = tid >> 6, ln = tid & 63, lr = ln & 15, lg = ln >> 4;
  const int bid = blockIdx.x;
  const int b = bid >> 1, dir = bid & 1;
  const int nm = b / TDIM, t = b - nm * TDIM;
  const size_t base = (size_t)nm * CD * (TDIM * LSEQ) + (size_t)t * LSEQ;
  const int ra0 = (lr < LSEQ) ? lr : (LSEQ - 1);
  const int ra1 = (16 + lr < LSEQ) ? (16 + lr) : (LSEQ - 1);

#pragma unroll
  for (int k = 0; k < 11; ++k) {
    int idx = tid + k * 256;
    int c = idx / LSEQ, v = idx - c * LSEQ;
    xs[v * XS_LD + c] = f2bf(x[base + (size_t)c * (TDIM * LSEQ) + v]);
  }
  __syncthreads();
  {
    bf16x8 afr[2][4];
#pragma unroll
    for (int kt = 0; kt < 4; ++kt) {
      afr[0][kt] = *(const bf16x8*)&xs[ra0 * XS_LD + kt * 32 + lg * 8];
      afr[1][kt] = *(const bf16x8*)&xs[ra1 * XS_LD + kt * 32 + lg * 8];
    }
    const u16* ih = ws + (dir ? WS_B_IN_HI : WS_F_IN_HI);
    const u16* il = ws + (dir ? WS_B_IN_LO : WS_F_IN_LO);
    u16* dst = (wv < 2) ? xiD : zD;
    const bool isz = (wv >= 2);
    const int cb0 = (wv & 1) * 128;
#pragma unroll
    for (int half = 0; half < 2; ++half) {
      f32x4 acc[2][4];
#pragma unroll
      for (int m = 0; m < 2; ++m)
#pragma unroll
        for (int n = 0; n < 4; ++n) acc[m][n] = f32x4{0.f, 0.f, 0.f, 0.f};
#pragma unroll
      for (int kt = 0; kt < 4; ++kt) {
        bf16x8 bh[4], bl[4];
#pragma unroll
        for (int n = 0; n < 4; ++n) {
          const int off = (wv * 128 + (half * 4 + n) * 16 + lr) * 128 + kt * 32 + lg * 8;
          bh[n] = *(const bf16x8*)(ih + off);
          bl[n] = *(const bf16x8*)(il + off);
        }
#pragma unroll
        for (int n = 0; n < 4; ++n) {
          acc[0][n] = __builtin_amdgcn_mfma_f32_16x16x32_bf16(afr[0][kt], bh[n], acc[0][n], 0, 0, 0);
          acc[0][n] = __builtin_amdgcn_mfma_f32_16x16x32_bf16(afr[0][kt], bl[n], acc[0][n], 0, 0, 0);
          acc[1][n] = __builtin_amdgcn_mfma_f32_16x16x32_bf16(afr[1][kt], bh[n], acc[1][n], 0, 0, 0);
          acc[1][n] = __builtin_amdgcn_mfma_f32_16x16x32_bf16(afr[1][kt], bl[n], acc[1][n], 0, 0, 0);
        }
      }
#pragma unroll
      for (int m = 0; m < 2; ++m)
#pragma unroll
        for (int n = 0; n < 4; ++n)
#pragma unroll
          for (int j = 0; j < 4; ++j) {
            int row = 16 * m + lg * 4 + j;
            if (row < LSEQ) {
              int rr = dir ? (LSEQ - 1 - row) : row;
              float v = acc[m][n][j];
              if (isz) v = v * sigm(v);
              dst[rr * XI_LD + cb0 + half * 64 + n * 16 + lr] = f2bf(v);
            }
          }
    }
  }
  __syncthreads();
  {
    const int d = tid;
    const float* cw  = dir ? b_conv_w : f_conv_w;
    const float* cbp = dir ? b_conv_b : f_conv_b;
    float4 w4 = *(const float4*)(cw + d * 4);
    float bb = cbp[d];
    float w0 = 0.f, w1 = 0.f, w2 = 0.f;
    float nxt = bf2f(xiD[d]);
#pragma unroll
    for (int l = 0; l < LSEQ; ++l) {
      float w3 = nxt;
      if (l + 1 < LSEQ) nxt = bf2f(xiD[(l + 1) * XI_LD + d]);
      float a = fmaf(w0, w4.x, bb);
      a = fmaf(w1, w4.y, a);
      a = fmaf(w2, w4.z, a);
      a = fmaf(w3, w4.w, a);
      float s = a * sigm(a);
      xiD[l * XI_LD + d] = f2bf(s);
      w0 = w1; w1 = w2; w2 = w3;
    }
  }
  __syncthreads();
  for (int tt = wv; tt < 6; tt += 4) {
    const int mt = tt / 3, nt = tt - mt * 3;
    const u16* xph = ws + (dir ? WS_B_XP_HI : WS_F_XP_HI);
    const u16* xpl = ws + (dir ? WS_B_XP_LO : WS_F_XP_LO);
    const int raa = (mt * 16 + lr < LSEQ) ? (mt * 16 + lr) : (LSEQ - 1);
    f32x4 acc = f32x4{0.f, 0.f, 0.f, 0.f};
    const u16* bh_p = xph + (nt * 16 + lr) * 256 + lg * 8;
    const u16* bl_p = xpl + (nt * 16 + lr) * 256 + lg * 8;
#pragma unroll
    for (int kt = 0; kt < 8; kt += 2) {
      bf16x8 a0  = *(const bf16x8*)&xiD[raa * XI_LD + kt * 32 + lg * 8];
      bf16x8 a1  = *(const bf16x8*)&xiD[raa * XI_LD + (kt + 1) * 32 + lg * 8];
      bf16x8 bh0 = *(const bf16x8*)(bh_p + kt * 32);
      bf16x8 bl0 = *(const bf16x8*)(bl_p + kt * 32);
      bf16x8 bh1 = *(const bf16x8*)(bh_p + (kt + 1) * 32);
      bf16x8 bl1 = *(const bf16x8*)(bl_p + (kt + 1) * 32);
      acc = __builtin_amdgcn_mfma_f32_16x16x32_bf16(a0, bh0, acc, 0, 0, 0);
      acc = __builtin_amdgcn_mfma_f32_16x16x32_bf16(a0, bl0, acc, 0, 0, 0);
      acc = __builtin_amdgcn_mfma_f32_16x16x32_bf16(a1, bh1, acc, 0, 0, 0);
      acc = __builtin_amdgcn_mfma_f32_16x16x32_bf16(a1, bl1, acc, 0, 0, 0);
    }
    const int col = nt * 16 + lr;
#pragma unroll
    for (int j = 0; j < 4; ++j) {
      int row = mt * 16 + lg * 4 + j;
      if (row < LSEQ) {
        if (col < 8) dtD[row * 8 + col] = acc[j];
        else if (col < 40) bcD[row * 32 + (col - 8)] = acc[j];
      }
    }
  }
  __syncthreads();
  {
    const int d = tid;
    const float* dtw  = dir ? b_dt_w : f_dt_w;
    const float* dtb  = dir ? b_dt_b : f_dt_b;
    const float* Alog = dir ? b_Alog : f_Alog;
    const float* Dp   = dir ? b_D : f_D;
    float4 dw0 = *(const float4*)(dtw + d * 8);
    float4 dw1 = *(const float4*)(dtw + d * 8 + 4);
    const float dtbv = dtb[d];
    float Av2[16];
#pragma unroll
    for (int s4 = 0; s4 < 4; ++s4) {
      float4 a = *(const float4*)(Alog + d * 16 + s4 * 4);
      Av2[s4 * 4 + 0] = -__expf(a.x) * 1.44269504f;
      Av2[s4 * 4 + 1] = -__expf(a.y) * 1.44269504f;
      Av2[s4 * 4 + 2] = -__expf(a.z) * 1.44269504f;
      Av2[s4 * 4 + 3] = -__expf(a.w) * 1.44269504f;
    }
    const float Dd = Dp[d];
    u16* wsY = ws + WS_MONO_Y + (size_t)b * 11264 + dir * 5632;
    const int r0 = dir ? (LSEQ - 1) : 0;
    const int rstep = dir ? -1 : 1;
    auto softp8 = [&](float4 q0, float4 q1) -> float {
      float sdt = dtbv;
      sdt = fmaf(q0.x, dw0.x, sdt); sdt = fmaf(q0.y, dw0.y, sdt);
      sdt = fmaf(q0.z, dw0.z, sdt); sdt = fmaf(q0.w, dw0.w, sdt);
      sdt = fmaf(q1.x, dw1.x, sdt); sdt = fmaf(q1.y, dw1.y, sdt);
      sdt = fmaf(q1.z, dw1.z, sdt); sdt = fmaf(q1.w, dw1.w, sdt);
      return (sdt > 20.f) ? sdt : __logf(1.f + __expf(sdt));
    };
    float h[16];
#pragma unroll
    for (int s = 0; s < 16; ++s) h[s] = 0.f;
#define SC(s, bv, cv) { float dA = __builtin_amdgcn_exp2f(dtv * Av2[s]); \
      h[s] = fmaf(dA, h[s], du * (bv)); \
      acc = fmaf(h[s], (cv), acc); }
    auto STEP = [&](int l, float dtv) {
      float u = bf2f(xiD[l * XI_LD + d]);
      float g = bf2f(zD[l * XI_LD + d]);
      float4 b0 = *(const float4*)(bcD + l * 32);
      float4 b1 = *(const float4*)(bcD + l * 32 + 4);
      float4 b2 = *(const float4*)(bcD + l * 32 + 8);
      float4 b3 = *(const float4*)(bcD + l * 32 + 12);
      float4 c0 = *(const float4*)(bcD + l * 32 + 16);
      float4 c1 = *(const float4*)(bcD + l * 32 + 20);
      float4 c2 = *(const float4*)(bcD + l * 32 + 24);
      float4 c3 = *(const float4*)(bcD + l * 32 + 28);
      float du = dtv * u;
      float acc = 0.f;
      SC(0, b0.x, c0.x) SC(1, b0.y, c0.y) SC(2, b0.z, c0.z) SC(3, b0.w, c0.w)
      SC(4, b1.x, c1.x) SC(5, b1.y, c1.y) SC(6, b1.z, c1.z) SC(7, b1.w, c1.w)
      SC(8, b2.x, c2.x) SC(9, b2.y, c2.y) SC(10, b2.z, c2.z) SC(11, b2.w, c2.w)
      SC(12, b3.x, c3.x) SC(13, b3.y, c3.y) SC(14, b3.z, c3.z) SC(15, b3.w, c3.w)
      float yo = fmaf(u, Dd, acc) * g;
      wsY[(r0 + rstep * l) * DI + d] = f2bf(yo);
    };
#undef SC
    float4 qa0 = *(const float4*)(dtD + 0);
    float4 qa1 = *(const float4*)(dtD + 4);
    float4 qb0 = *(const float4*)(dtD + 8);
    float4 qb1 = *(const float4*)(dtD + 12);
    float dtvA = softp8(qa0, qa1);
    float dtvB = softp8(qb0, qb1);
    for (int ll = 0; ll < LSEQ; ll += 2) {
      const int l2 = (ll + 2 < LSEQ) ? (ll + 2) : (LSEQ - 2);
      qa0 = *(const float4*)(dtD + l2 * 8);
      qa1 = *(const float4*)(dtD + l2 * 8 + 4);
      qb0 = *(const float4*)(dtD + l2 * 8 + 8);
      qb1 = *(const float4*)(dtD + l2 * 8 + 12);
      STEP(ll, dtvA);
      STEP(ll + 1, dtvB);
      dtvA = softp8(qa0, qa1);
      dtvB = softp8(qb0, qb1);
    }
  }
}

__global__ __launch_bounds__(256, 6) void fold_ln_kernel(
    const float* __restrict__ ln_w, const float* __restrict__ ln_b,
    const u16* __restrict__ ws, float* __restrict__ out)
{
  __shared__ __align__(16) u16 pool[11616];
  const int tid = threadIdx.x;
  const int wv = tid >> 6, ln = tid & 63, lr = ln & 15, lg = ln >> 4;
  const int b = blockIdx.x;
  const int nm = b / TDIM, t = b - nm * TDIM;
  const size_t base = (size_t)nm * CD * (TDIM * LSEQ) + (size_t)t * LSEQ;
  const u16* wsY = ws + WS_MONO_Y + (size_t)b * 11264;

  for (int idx = tid; idx < 2 * LSEQ * 32; idx += 256) {
    int dirc = idx / 704, r = idx - dirc * 704;
    int l = r >> 5, ch = (r & 31) * 8;
    *(bf16x8*)&pool[dirc * 5808 + l * YLD + ch] =
        *(const bf16x8*)(wsY + dirc * 5632 + l * 256 + ch);
  }
  __syncthreads();
  const int ra0 = (lr < LSEQ) ? lr : (LSEQ - 1);
  const int ra1 = (16 + lr < LSEQ) ? (16 + lr) : (LSEQ - 1);
  f32x4 acc[2][2];
#pragma unroll
  for (int m = 0; m < 2; ++m)
#pragma unroll
    for (int n = 0; n < 2; ++n) acc[m][n] = f32x4{0.f, 0.f, 0.f, 0.f};
#pragma unroll
  for (int dirc = 0; dirc < 2; ++dirc) {
    const u16* wp = ws + (dirc ? WS_B_OUT : WS_F_OUT);
    const u16* yD = pool + dirc * 5808;
#pragma unroll
    for (int kt = 0; kt < 8; ++kt) {
      bf16x8 a0 = *(const bf16x8*)&yD[ra0 * YLD + kt * 32 + lg * 8];
      bf16x8 a1 = *(const bf16x8*)&yD[ra1 * YLD + kt * 32 + lg * 8];
#pragma unroll
      for (int n = 0; n < 2; ++n) {
        bf16x8 bw = *(const bf16x8*)(wp + (wv * 32 + n * 16 + lr) * 256 + kt * 32 + lg * 8);
        acc[0][n] = __builtin_amdgcn_mfma_f32_16x16x32_bf16(a0, bw, acc[0][n], 0, 0, 0);
        acc[1][n] = __builtin_amdgcn_mfma_f32_16x16x32_bf16(a1, bw, acc[1][n], 0, 0, 0);
      }
    }
  }
  __syncthreads();
  float* y2 = (float*)pool;
#pragma unroll
  for (int m = 0; m < 2; ++m)
#pragma unroll
    for (int n = 0; n < 2; ++n)
#pragma unroll
      for (int j = 0; j < 4; ++j) {
        int row = 16 * m + lg * 4 + j;
        if (row < LSEQ) y2[row * Y2_LD + wv * 32 + n * 16 + lr] = acc[m][n][j];
      }
  __syncthreads();
  float* mu_s = (float*)(pool + 5808);
  float* rs_s = mu_s + LSEQ;
  for (int l = wv; l < LSEQ; l += 4) {
    float v1 = y2[l * Y2_LD + ln];
    float v2 = y2[l * Y2_LD + 64 + ln];
    float s = v1 + v2;
    float sq = v1 * v1 + v2 * v2;
#pragma unroll
    for (int m = 1; m < 64; m <<= 1) {
      s  += __shfl_xor(s, m, 64);
      sq += __shfl_xor(sq, m, 64);
    }
    if (ln == 0) {
      float mu = s * (1.0f / 128.0f);
      float var = sq * (1.0f / 128.0f) - mu * mu;
      mu_s[l] = mu;
      rs_s[l] = rsqrtf(var + 1e-5f);
    }
  }
  __syncthreads();
  for (int idx = tid; idx < LSEQ * CD; idx += 256) {
    int c = idx / LSEQ, v = idx - c * LSEQ;
    float yv = y2[v * Y2_LD + c];
    float o = (yv - mu_s[v]) * rs_s[v] * ln_w[c] + ln_b[c];
    out[base + (size_t)c * (TDIM * LSEQ) + v] = o;
  }
}

}  // namespace

extern "C" void kernel_launch(void* const* d_in, const int* in_sizes, int n_in,
                              void* d_out, int out_size, void* d_ws, size_t ws_size,
                              hipStream_t stream) {
  (void)in_sizes; (void)n_in; (void)out_size;
  const float* p[22];
  for (int i = 0; i < 22; ++i) p[i] = (const float*)d_in[i];
  u16* ws = (u16*)d_ws;
  prep_weights<<<dim3((WS_TOTAL + 255) / 256), dim3(256), 0, stream>>>(
      p[1], p[10], p[4], p[13], ws);
  prep_av2<<<dim3(32), dim3(256), 0, stream>>>(p[7], p[16], ws);
  prep_fold<<<dim3(256), dim3(256), 0, stream>>>(p[9], p[18], p[19], ws);
  if (ws_size >= NEED_SPLIT) {
    mamba_gemm_kernel<<<dim3(32 * 64 * 2), dim3(256), 0, stream>>>(
        p[0], p[2], p[3], p[11], p[12], ws);
    scan_fold_ln_kernel<<<dim3(32 * 64), dim3(512), 0, stream>>>(
        p[5], p[6], p[8], p[14], p[15], p[17], p[20], p[21], ws, (float*)d_out);
  } else {
    mamba_scan_mono<<<dim3(32 * 64 * 2), dim3(256), 0, stream>>>(
        p[0],
        p[2], p[3], p[5], p[6], p[7], p[8],
        p[11], p[12], p[14], p[15], p[16], p[17],
        ws);
    fold_ln_kernel<<<dim3(32 * 64), dim3(256), 0, stream>>>(
        p[20], p[21], ws, (float*)d_out);
  }
}

// Round 7
// 287.793 us; speedup vs baseline: 1.5744x; 1.5744x over previous
//
#include <hip/hip_runtime.h>
#include <hip/hip_bf16.h>
#include <math.h>

namespace {

typedef unsigned short u16;
typedef unsigned int u32;

constexpr int LSEQ = 22, CD = 128, DI = 256, TDIM = 64;

// LDS strides (u16). Row stride mod 32 words == 2 -> 2-way bank alias (free,
// m136). Verified R4/R5: bank conflicts 2.16M -> 471K with 132/260.
constexpr int XS_LD = 132;
constexpr int XI_LD = 260;
constexpr int Y2_LD = 132;   // f32 (K2)

// ---- K1 pool: xi[0,5720) z[5720,11440) dtbc[11440,13200), pad to 14000 ----
//   xs [0,2904) overlays xi (xs dead after afr loads; intra-P1 barrier —
//   validated R4/R5). Pad pins EXACTLY 5 blocks/CU (28 KB; 6 blocks thrashes
//   L2 per R5: FETCH 61->313 MB). All intermediates stay in LDS (R4/R6:
//   global roundtrips -> 0.3-1.1 GB HBM fetch, 1.5-2x slower).
constexpr int K1_XI   = 0;
constexpr int K1_Z    = 5720;
constexpr int K1_DTBC = 11440;
constexpr int K1_N    = 14000;   // 28 KB -> 5 blocks/CU

// ---- K2 pool ----
constexpr int K2_N  = 11616;     // 23.2 KB

// ws segments (u16 element offsets)
constexpr int WS_F_IN_HI = 0;        // 512x128
constexpr int WS_F_IN_LO = 65536;
constexpr int WS_B_IN_HI = 131072;
constexpr int WS_B_IN_LO = 196608;
constexpr int WS_F_OUT   = 262144;   // 128x256: prep_fold -> Wf = fuse[:, :128] @ f_out_w
constexpr int WS_B_OUT   = 294912;   // 128x256: prep_fold -> Wb = fuse[:, 128:] @ b_out_w
constexpr int WS_F_XP_HI = 360448;   // 48x256 (rows 40..47 zero)
constexpr int WS_F_XP_LO = 372736;
constexpr int WS_B_XP_HI = 385024;
constexpr int WS_B_XP_LO = 397312;
constexpr int WS_TOTAL   = 409600;   // 800 KiB
// y staging: per (nm,t): 2 dirs x 22 x 256 bf16 = 11264 u16; bwd pre-un-reversed.
constexpr int WS_Y       = 409600;

typedef __attribute__((ext_vector_type(8))) short bf16x8;
typedef __attribute__((ext_vector_type(4))) float f32x4;

__device__ __forceinline__ u16 f2bf(float f) {
  __bf16 b = (__bf16)f;
  return *reinterpret_cast<u16*>(&b);
}
__device__ __forceinline__ float bf2f(u16 h) {
  return __uint_as_float(((u32)h) << 16);
}
// sigmoid without the IEEE-div sequence: 1/(1+exp(-x)) via v_exp + v_rcp
__device__ __forceinline__ float sigm(float x) {
  float e = __builtin_amdgcn_exp2f(-1.44269504f * x);
  return __builtin_amdgcn_rcpf(1.0f + e);
}

__global__ void prep_weights(const float* __restrict__ f_in, const float* __restrict__ b_in,
                             const float* __restrict__ f_xp, const float* __restrict__ b_xp,
                             u16* __restrict__ ws) {
  int i = blockIdx.x * 256 + threadIdx.x;
  if (i >= WS_TOTAL) return;
  u16 r = 0;
  if (i < WS_F_IN_LO) {
    r = f2bf(f_in[i]);
  } else if (i < WS_B_IN_HI) {
    float v = f_in[i - WS_F_IN_LO];
    r = f2bf(v - bf2f(f2bf(v)));
  } else if (i < WS_B_IN_LO) {
    r = f2bf(b_in[i - WS_B_IN_HI]);
  } else if (i < WS_F_OUT) {
    float v = b_in[i - WS_B_IN_LO];
    r = f2bf(v - bf2f(f2bf(v)));
  } else if (i < WS_F_XP_HI) {
    r = 0;  // OUT slots: filled by prep_fold
  } else if (i < WS_F_XP_LO) {
    int j = i - WS_F_XP_HI, n = j >> 8, k = j & 255;
    r = (n < 40) ? f2bf(f_xp[n * 256 + k]) : (u16)0;
  } else if (i < WS_B_XP_HI) {
    int j = i - WS_F_XP_LO, n = j >> 8, k = j & 255;
    if (n < 40) { float v = f_xp[n * 256 + k]; r = f2bf(v - bf2f(f2bf(v))); } else r = 0;
  } else if (i < WS_B_XP_LO) {
    int j = i - WS_B_XP_HI, n = j >> 8, k = j & 255;
    r = (n < 40) ? f2bf(b_xp[n * 256 + k]) : (u16)0;
  } else {
    int j = i - WS_B_XP_LO, n = j >> 8, k = j & 255;
    if (n < 40) { float v = b_xp[n * 256 + k]; r = f2bf(v - bf2f(f2bf(v))); } else r = 0;
  }
  ws[i] = r;
}

// Wf = fuse_w[:, :128] @ f_out_w ; Wb = fuse_w[:, 128:] @ b_out_w  (each 128x256)
__global__ void prep_fold(const float* __restrict__ f_out, const float* __restrict__ b_out,
                          const float* __restrict__ fuse, u16* __restrict__ ws) {
  int i = blockIdx.x * 256 + threadIdx.x;   // 65536 outputs
  int half = i >> 15;
  int j = i & 32767;
  int c = j >> 8, d = j & 255;
  const float* ow = half ? b_out : f_out;
  const float* fw = fuse + c * 256 + half * 128;
  float acc = 0.f;
#pragma unroll 4
  for (int k = 0; k < 128; ++k) acc = fmaf(fw[k], ow[k * 256 + d], acc);
  ws[(half ? WS_B_OUT : WS_F_OUT) + c * 256 + d] = f2bf(acc);
}

// ============ K1: per (nm, t, dir) — in_proj, conv, x_proj, scan ============
// R2 config (best measured: 251 us): (256,5), 5 blocks/CU, all LDS dataflow.
__global__ __launch_bounds__(256, 5) void mamba_scan_kernel(
    const float* __restrict__ x,
    const float* __restrict__ f_conv_w, const float* __restrict__ f_conv_b,
    const float* __restrict__ f_dt_w, const float* __restrict__ f_dt_b,
    const float* __restrict__ f_Alog, const float* __restrict__ f_D,
    const float* __restrict__ b_conv_w, const float* __restrict__ b_conv_b,
    const float* __restrict__ b_dt_w, const float* __restrict__ b_dt_b,
    const float* __restrict__ b_Alog, const float* __restrict__ b_D,
    u16* __restrict__ ws)
{
  __shared__ __align__(16) u16 pool[K1_N];

  u16* xs  = pool;                        // [0,2904) overlays xi
  u16* xiD = pool + K1_XI;
  u16* zD  = pool + K1_Z;
  float* dtD = (float*)(pool + K1_DTBC);  // f32[22][8]
  float* bcD = dtD + 176;                 // f32[22][32]

  const int tid = threadIdx.x;
  const int wv = tid >> 6, ln = tid & 63, lr = ln & 15, lg = ln >> 4;
  const int bid = blockIdx.x;
  const int b = bid >> 1, dir = bid & 1;
  const int nm = b / TDIM, t = b - nm * TDIM;
  const size_t base = (size_t)nm * CD * (TDIM * LSEQ) + (size_t)t * LSEQ;

  const int ra0 = (lr < LSEQ) ? lr : (LSEQ - 1);
  const int ra1 = (16 + lr < LSEQ) ? (16 + lr) : (LSEQ - 1);

  // ---- stage xs (bf16) ----
#pragma unroll
  for (int k = 0; k < 11; ++k) {
    int idx = tid + k * 256;
    int c = idx / LSEQ, v = idx - c * LSEQ;
    xs[v * XS_LD + c] = f2bf(x[base + (size_t)c * (TDIM * LSEQ) + v]);
  }
  __syncthreads();

  // ---- P1: in_proj MFMA (one dir). Wave wv owns 128 output cols. ----
  {
    bf16x8 afr[2][4];
#pragma unroll
    for (int kt = 0; kt < 4; ++kt) {
      afr[0][kt] = *(const bf16x8*)&xs[ra0 * XS_LD + kt * 32 + lg * 8];
      afr[1][kt] = *(const bf16x8*)&xs[ra1 * XS_LD + kt * 32 + lg * 8];
    }
    __syncthreads();   // all waves done reading xs; xi may overwrite xs region

    const u16* ih = ws + (dir ? WS_B_IN_HI : WS_F_IN_HI);
    const u16* il = ws + (dir ? WS_B_IN_LO : WS_F_IN_LO);
    u16* dst = (wv < 2) ? xiD : zD;       // cols 0..255 -> xi, 256..511 -> z(g)
    const bool isz = (wv >= 2);
    const int cb0 = (wv & 1) * 128;
#pragma unroll
    for (int half = 0; half < 2; ++half) {   // two 64-col sub-tiles to cap VGPRs
      f32x4 acc[2][4];
#pragma unroll
      for (int m = 0; m < 2; ++m)
#pragma unroll
        for (int n = 0; n < 4; ++n) acc[m][n] = f32x4{0.f, 0.f, 0.f, 0.f};
#pragma unroll
      for (int kt = 0; kt < 4; ++kt) {
        bf16x8 bh[4], bl[4];
#pragma unroll
        for (int n = 0; n < 4; ++n) {      // 8 loads in flight before MFMAs
          const int off = (wv * 128 + (half * 4 + n) * 16 + lr) * 128 + kt * 32 + lg * 8;
          bh[n] = *(const bf16x8*)(ih + off);
          bl[n] = *(const bf16x8*)(il + off);
        }
#pragma unroll
        for (int n = 0; n < 4; ++n) {
          acc[0][n] = __builtin_amdgcn_mfma_f32_16x16x32_bf16(afr[0][kt], bh[n], acc[0][n], 0, 0, 0);
          acc[0][n] = __builtin_amdgcn_mfma_f32_16x16x32_bf16(afr[0][kt], bl[n], acc[0][n], 0, 0, 0);
          acc[1][n] = __builtin_amdgcn_mfma_f32_16x16x32_bf16(afr[1][kt], bh[n], acc[1][n], 0, 0, 0);
          acc[1][n] = __builtin_amdgcn_mfma_f32_16x16x32_bf16(afr[1][kt], bl[n], acc[1][n], 0, 0, 0);
        }
      }
#pragma unroll
      for (int m = 0; m < 2; ++m)
#pragma unroll
        for (int n = 0; n < 4; ++n)
#pragma unroll
          for (int j = 0; j < 4; ++j) {
            int row = 16 * m + lg * 4 + j;
            if (row < LSEQ) {
              int rr = dir ? (LSEQ - 1 - row) : row;    // bwd: store reversed
              int col = cb0 + half * 64 + n * 16 + lr;
              float v = acc[m][n][j];
              if (isz) v = v * sigm(v);                 // g = silu(z)
              dst[rr * XI_LD + col] = f2bf(v);
            }
          }
    }
  }
  __syncthreads();

  // ---- P2: causal depthwise conv + SiLU, in-place, 1-ahead LDS prefetch ----
  {
    const int d = tid;
    const float* cw  = dir ? b_conv_w : f_conv_w;
    const float* cbp = dir ? b_conv_b : f_conv_b;
    float4 w4 = *(const float4*)(cw + d * 4);
    float bb = cbp[d];
    float w0 = 0.f, w1 = 0.f, w2 = 0.f;
    float nxt = bf2f(xiD[d]);            // l = 0
#pragma unroll
    for (int l = 0; l < LSEQ; ++l) {
      float w3 = nxt;
      if (l + 1 < LSEQ) nxt = bf2f(xiD[(l + 1) * XI_LD + d]);   // prefetch before write
      float a = fmaf(w0, w4.x, bb);
      a = fmaf(w1, w4.y, a);
      a = fmaf(w2, w4.z, a);
      a = fmaf(w3, w4.w, a);
      float s = a * sigm(a);
      xiD[l * XI_LD + d] = f2bf(s);      // xc overwrites xi
      w0 = w1; w1 = w2; w2 = w3;
    }
  }
  __syncthreads();

  // ---- P3: x_proj MFMA (6 wave-tiles over 4 waves) -> dt/bc f32 in LDS ----
  for (int tt = wv; tt < 6; tt += 4) {
    const int mt = tt / 3, nt = tt - mt * 3;
    const u16* xph = ws + (dir ? WS_B_XP_HI : WS_F_XP_HI);
    const u16* xpl = ws + (dir ? WS_B_XP_LO : WS_F_XP_LO);
    const int raa = (mt * 16 + lr < LSEQ) ? (mt * 16 + lr) : (LSEQ - 1);
    f32x4 acc = f32x4{0.f, 0.f, 0.f, 0.f};
    const u16* bh_p = xph + (nt * 16 + lr) * 256 + lg * 8;
    const u16* bl_p = xpl + (nt * 16 + lr) * 256 + lg * 8;
#pragma unroll
    for (int kt = 0; kt < 8; kt += 2) {
      bf16x8 a0  = *(const bf16x8*)&xiD[raa * XI_LD + kt * 32 + lg * 8];
      bf16x8 a1  = *(const bf16x8*)&xiD[raa * XI_LD + (kt + 1) * 32 + lg * 8];
      bf16x8 bh0 = *(const bf16x8*)(bh_p + kt * 32);
      bf16x8 bl0 = *(const bf16x8*)(bl_p + kt * 32);
      bf16x8 bh1 = *(const bf16x8*)(bh_p + (kt + 1) * 32);
      bf16x8 bl1 = *(const bf16x8*)(bl_p + (kt + 1) * 32);
      acc = __builtin_amdgcn_mfma_f32_16x16x32_bf16(a0, bh0, acc, 0, 0, 0);
      acc = __builtin_amdgcn_mfma_f32_16x16x32_bf16(a0, bl0, acc, 0, 0, 0);
      acc = __builtin_amdgcn_mfma_f32_16x16x32_bf16(a1, bh1, acc, 0, 0, 0);
      acc = __builtin_amdgcn_mfma_f32_16x16x32_bf16(a1, bl1, acc, 0, 0, 0);
    }
    const int col = nt * 16 + lr;
#pragma unroll
    for (int j = 0; j < 4; ++j) {
      int row = mt * 16 + lg * 4 + j;
      if (row < LSEQ) {
        if (col < 8) dtD[row * 8 + col] = acc[j];
        else if (col < 40) bcD[row * 32 + (col - 8)] = acc[j];
      }
    }
  }
  __syncthreads();

  // ---- P4: pipelined softplus(dt) + selective scan + D-skip + gate ----
  // FULLY UNROLLED (11 static iterations): exposes all LDS addresses as
  // constants so the compiler can hoist ds_reads across steps under the
  // trans/fma dependency chain.
  {
    const int d = tid;
    const float* dtw  = dir ? b_dt_w : f_dt_w;
    const float* dtb  = dir ? b_dt_b : f_dt_b;
    const float* Alog = dir ? b_Alog : f_Alog;
    const float* Dp   = dir ? b_D : f_D;

    float4 dw0 = *(const float4*)(dtw + d * 8);
    float4 dw1 = *(const float4*)(dtw + d * 8 + 4);
    const float dtbv = dtb[d];
    float Av2[16];           // -exp(Alog) * log2(e): dA = exp2(dtv * Av2)
#pragma unroll
    for (int s4 = 0; s4 < 4; ++s4) {
      float4 a = *(const float4*)(Alog + d * 16 + s4 * 4);
      Av2[s4 * 4 + 0] = -__expf(a.x) * 1.44269504f;
      Av2[s4 * 4 + 1] = -__expf(a.y) * 1.44269504f;
      Av2[s4 * 4 + 2] = -__expf(a.z) * 1.44269504f;
      Av2[s4 * 4 + 3] = -__expf(a.w) * 1.44269504f;
    }
    const float Dd = Dp[d];
    u16* wsY = ws + WS_Y + (size_t)b * 11264 + dir * 5632;
    const int r0 = dir ? (LSEQ - 1) : 0;
    const int rstep = dir ? -1 : 1;

    auto softp8 = [&](float4 q0, float4 q1) -> float {
      float sdt = dtbv;
      sdt = fmaf(q0.x, dw0.x, sdt); sdt = fmaf(q0.y, dw0.y, sdt);
      sdt = fmaf(q0.z, dw0.z, sdt); sdt = fmaf(q0.w, dw0.w, sdt);
      sdt = fmaf(q1.x, dw1.x, sdt); sdt = fmaf(q1.y, dw1.y, sdt);
      sdt = fmaf(q1.z, dw1.z, sdt); sdt = fmaf(q1.w, dw1.w, sdt);
      return (sdt > 20.f) ? sdt : __logf(1.f + __expf(sdt));
    };

    float h[16];
#pragma unroll
    for (int s = 0; s < 16; ++s) h[s] = 0.f;

#define SC(s, bv, cv) { float dA = __builtin_amdgcn_exp2f(dtv * Av2[s]); \
      h[s] = fmaf(dA, h[s], du * (bv)); \
      acc = fmaf(h[s], (cv), acc); }
    auto STEP = [&](int l, float dtv) {
      float u = bf2f(xiD[l * XI_LD + d]);      // independent reads first
      float g = bf2f(zD[l * XI_LD + d]);
      float4 b0 = *(const float4*)(bcD + l * 32);
      float4 b1 = *(const float4*)(bcD + l * 32 + 4);
      float4 b2 = *(const float4*)(bcD + l * 32 + 8);
      float4 b3 = *(const float4*)(bcD + l * 32 + 12);
      float4 c0 = *(const float4*)(bcD + l * 32 + 16);
      float4 c1 = *(const float4*)(bcD + l * 32 + 20);
      float4 c2 = *(const float4*)(bcD + l * 32 + 24);
      float4 c3 = *(const float4*)(bcD + l * 32 + 28);
      float du = dtv * u;
      float acc = 0.f;
      SC(0, b0.x, c0.x) SC(1, b0.y, c0.y) SC(2, b0.z, c0.z) SC(3, b0.w, c0.w)
      SC(4, b1.x, c1.x) SC(5, b1.y, c1.y) SC(6, b1.z, c1.z) SC(7, b1.w, c1.w)
      SC(8, b2.x, c2.x) SC(9, b2.y, c2.y) SC(10, b2.z, c2.z) SC(11, b2.w, c2.w)
      SC(12, b3.x, c3.x) SC(13, b3.y, c3.y) SC(14, b3.z, c3.z) SC(15, b3.w, c3.w)
      float yo = fmaf(u, Dd, acc) * g;
      wsY[(r0 + rstep * l) * DI + d] = f2bf(yo);
    };
#undef SC

    // 2-step softplus pipeline, fully unrolled outer loop.
    float4 qa0 = *(const float4*)(dtD + 0);
    float4 qa1 = *(const float4*)(dtD + 4);
    float4 qb0 = *(const float4*)(dtD + 8);
    float4 qb1 = *(const float4*)(dtD + 12);
    float dtvA = softp8(qa0, qa1);
    float dtvB = softp8(qb0, qb1);

#pragma unroll
    for (int ll = 0; ll < LSEQ; ll += 2) {
      const int l2 = (ll + 2 < LSEQ) ? (ll + 2) : (LSEQ - 2);   // constexpr after unroll
      qa0 = *(const float4*)(dtD + l2 * 8);
      qa1 = *(const float4*)(dtD + l2 * 8 + 4);
      qb0 = *(const float4*)(dtD + l2 * 8 + 8);
      qb1 = *(const float4*)(dtD + l2 * 8 + 12);
      STEP(ll, dtvA);
      STEP(ll + 1, dtvB);
      dtvA = softp8(qa0, qa1);
      dtvB = softp8(qb0, qb1);
    }
  }
}

// ============ K2: per (nm, t) — folded out_proj/fuse + LayerNorm ============
__global__ __launch_bounds__(256, 6) void fold_ln_kernel(
    const float* __restrict__ ln_w, const float* __restrict__ ln_b,
    const u16* __restrict__ ws, float* __restrict__ out)
{
  __shared__ __align__(16) u16 pool[K2_N];

  const int tid = threadIdx.x;
  const int wv = tid >> 6, ln = tid & 63, lr = ln & 15, lg = ln >> 4;
  const int b = blockIdx.x;
  const int nm = b / TDIM, t = b - nm * TDIM;
  const size_t base = (size_t)nm * CD * (TDIM * LSEQ) + (size_t)t * LSEQ;
  const u16* wsY = ws + WS_Y + (size_t)b * 11264;

  // ---- stage y_f, y_b (both already in sequence order) ----
  for (int idx = tid; idx < 2 * LSEQ * 32; idx += 256) {   // 1408 x bf16x8
    int dirc = idx / 704, r = idx - dirc * 704;
    int l = r >> 5, ch = (r & 31) * 8;
    *(bf16x8*)&pool[dirc * 5808 + l * 264 + ch] =
        *(const bf16x8*)(wsY + dirc * 5632 + l * 256 + ch);
  }
  __syncthreads();

  const int ra0 = (lr < LSEQ) ? lr : (LSEQ - 1);
  const int ra1 = (16 + lr < LSEQ) ? (16 + lr) : (LSEQ - 1);

  // ---- y2 = y_f @ Wf.T + y_b @ Wb.T ----
  f32x4 acc[2][2];
#pragma unroll
  for (int m = 0; m < 2; ++m)
#pragma unroll
    for (int n = 0; n < 2; ++n) acc[m][n] = f32x4{0.f, 0.f, 0.f, 0.f};
#pragma unroll
  for (int dirc = 0; dirc < 2; ++dirc) {
    const u16* wp = ws + (dirc ? WS_B_OUT : WS_F_OUT);
    const u16* yD = pool + dirc * 5808;
#pragma unroll
    for (int kt = 0; kt < 8; ++kt) {
      bf16x8 a0 = *(const bf16x8*)&yD[ra0 * 264 + kt * 32 + lg * 8];
      bf16x8 a1 = *(const bf16x8*)&yD[ra1 * 264 + kt * 32 + lg * 8];
#pragma unroll
      for (int n = 0; n < 2; ++n) {
        bf16x8 bw = *(const bf16x8*)(wp + (wv * 32 + n * 16 + lr) * 256 + kt * 32 + lg * 8);
        acc[0][n] = __builtin_amdgcn_mfma_f32_16x16x32_bf16(a0, bw, acc[0][n], 0, 0, 0);
        acc[1][n] = __builtin_amdgcn_mfma_f32_16x16x32_bf16(a1, bw, acc[1][n], 0, 0, 0);
      }
    }
  }
  __syncthreads();   // all waves done reading yf/yb before overlay write

  float* y2 = (float*)pool;   // [22][132], overlays yf
#pragma unroll
  for (int m = 0; m < 2; ++m)
#pragma unroll
    for (int n = 0; n < 2; ++n)
#pragma unroll
      for (int j = 0; j < 4; ++j) {
        int row = 16 * m + lg * 4 + j;
        if (row < LSEQ) y2[row * Y2_LD + wv * 32 + n * 16 + lr] = acc[m][n][j];
      }
  __syncthreads();

  // ---- LayerNorm stats (one wave per row) ----
  float* mu_s = (float*)(pool + 5808);   // overlays yb
  float* rs_s = mu_s + LSEQ;
  for (int l = wv; l < LSEQ; l += 4) {
    float v1 = y2[l * Y2_LD + ln];
    float v2 = y2[l * Y2_LD + 64 + ln];
    float s = v1 + v2;
    float sq = v1 * v1 + v2 * v2;
#pragma unroll
    for (int m = 1; m < 64; m <<= 1) {
      s  += __shfl_xor(s, m, 64);
      sq += __shfl_xor(sq, m, 64);
    }
    if (ln == 0) {
      float mu = s * (1.0f / 128.0f);
      float var = sq * (1.0f / 128.0f) - mu * mu;
      mu_s[l] = mu;
      rs_s[l] = rsqrtf(var + 1e-5f);
    }
  }
  __syncthreads();

  // ---- normalize + transposed store ----
  for (int idx = tid; idx < LSEQ * CD; idx += 256) {
    int c = idx / LSEQ, v = idx - c * LSEQ;
    float yv = y2[v * Y2_LD + c];
    float o = (yv - mu_s[v]) * rs_s[v] * ln_w[c] + ln_b[c];
    out[base + (size_t)c * (TDIM * LSEQ) + v] = o;
  }
}

}  // namespace

extern "C" void kernel_launch(void* const* d_in, const int* in_sizes, int n_in,
                              void* d_out, int out_size, void* d_ws, size_t ws_size,
                              hipStream_t stream) {
  (void)in_sizes; (void)n_in; (void)ws_size; (void)out_size;
  const float* p[22];
  for (int i = 0; i < 22; ++i) p[i] = (const float*)d_in[i];
  u16* ws = (u16*)d_ws;
  prep_weights<<<dim3((WS_TOTAL + 255) / 256), dim3(256), 0, stream>>>(
      p[1], p[10], p[4], p[13], ws);
  prep_fold<<<dim3(256), dim3(256), 0, stream>>>(p[9], p[18], p[19], ws);
  mamba_scan_kernel<<<dim3(32 * 64 * 2), dim3(256), 0, stream>>>(
      p[0],
      p[2], p[3], p[5], p[6], p[7], p[8],
      p[11], p[12], p[14], p[15], p[16], p[17],
      ws);
  fold_ln_kernel<<<dim3(32 * 64), dim3(256), 0, stream>>>(
      p[20], p[21], ws, (float*)d_out);
}